// Round 1
// baseline (182.946 us; speedup 1.0000x reference)
//
#include <hip/hip_runtime.h>

// 2-layer GCN, padded-CSR gather + bf16-MFMA, 5 stream-ordered dispatches.
//
// LESSON (R6-R8, measured): grid.sync() costs ~250-300us EACH on MI355X.
// Do NOT fuse phases with grid.sync.
// LESSON (R9): mean degree 16 -- hide gather latency via INDEPENDENT chains
// (quarter-wave-per-node), not unroll depth.
// LESSON (R12): padded CSR (64 slots/node) kills the prefix scan.
// LESSON (R13/R14): (256,8) on k_gcn1 helps; scatter fused into the atomic
// pass regresses (random 4B stores + addr-dependency on atomic return).
// LESSON (R15-R17, measured): k_gcn1 pinned ~46.5us by the random-gather
// path -- insensitive to occupancy (41->64%), per-edge VALU work, and index
// width. 84MB HBM-side of 205MB logical = ~41% L2 miss, structural for a
// 12.8MB working set vs 4MB/XCD L2 on a random graph.
// LESSON (R18, measured): raising TLP on build phases (391->1563 / 782->3125
// blocks) is neutral -> atomic pass is ATOMIC-THROUGHPUT-bound, not
// latency-bound. It has idle HBM BW and VALU.
// R19: exploit that slack. Store xr = bf16(x) UNSCALED (no deg dependency)
// and apply dinv[src] at gather time (add8 -> fma8, VALU-neutral per R15-17).
// The 38.4MB conversion moves from serial-in-k_fill to overlapped-with-
// atomics in k_build. k_fill shrinks to scatter-only + dinv. rank stored as
// uchar (saves 4.8MB of rank traffic).
//
//   memset  : deg
//   k_build : rank[e]=atomicAdd(deg[dst],1) 2 edges/thread (uchar rank)
//             | xr = bf16(x) grid-stride (deg-independent, overlaps atomics)
//             | W1 -> bf16 B-fragment pack | b1/W2 pad
//   k_fill  : csrp[dst*64+rank] = (u16)src, 1 edge/thread
//             | dinv[n] = rsqrt(deg[n]+1)
//   k_gcn1  : per 16-node tile: gather A[n]=dinv_n*(sum dinv_s*xr[s]
//             + dinv_n*xr[n]) -> LDS, zd = dinv*(relu(A@W1+b1)@W2) via MFMA
//   k_gz    : out[i] = dinv_i*(sum_{s in N(i)} zd[s] + zd[i]) + b2

#define N_NODES 50000
#define N_EDGES 800000
#define D_FEAT  128
#define D_HID   500
#define NTILES  3125         // 50000 / 16
#define RB2     1563         // ceil(800000 / (256*2)) atomic blocks
#define CONVB   1563         // conversion blocks (overlap the atomic pass)
#define CSTRIDE 64           // padded CSR slots per node

typedef __bf16 bf16x8 __attribute__((ext_vector_type(8)));
typedef float  f32x4  __attribute__((ext_vector_type(4)));

static __device__ inline unsigned int f2bf(float f) {   // fp32 -> bf16 bits, RTNE
    unsigned int u = __float_as_uint(f);
    return (u + 0x7fffu + ((u >> 16) & 1u)) >> 16;
}
static __device__ inline float bf_lo(unsigned int u) { return __uint_as_float(u << 16); }
static __device__ inline float bf_hi(unsigned int u) { return __uint_as_float(u & 0xffff0000u); }

static __device__ inline void fma8(float* acc, uint4 u, float d) {
    acc[0] += d * bf_lo(u.x);
    acc[1] += d * bf_hi(u.x);
    acc[2] += d * bf_lo(u.y);
    acc[3] += d * bf_hi(u.y);
    acc[4] += d * bf_lo(u.z);
    acc[5] += d * bf_hi(u.z);
    acc[6] += d * bf_lo(u.w);
    acc[7] += d * bf_hi(u.w);
}

// ---- k_build: [0,RB2) atomic rank | [RB2,RB2+CONVB) xr convert |
// ----          32 W1-pack blocks | 1 pad block ----
__global__ __launch_bounds__(256) void k_build(const int* __restrict__ dst,
                                               const float* __restrict__ x,
                                               const float* __restrict__ W1,
                                               const float* __restrict__ b1,
                                               const float* __restrict__ W2,
                                               int* __restrict__ deg,
                                               unsigned char* __restrict__ rankb,
                                               uint2* __restrict__ xr,
                                               unsigned short* __restrict__ b_pk,
                                               float* __restrict__ b1p,
                                               float* __restrict__ w2p) {
    const int b = blockIdx.x, tid = threadIdx.x;
    if (b < RB2) {                                    // 2 atomic chains/thread
        int t2 = b * 256 + tid;
        if (t2 < N_EDGES / 2) {
            int e = t2 * 2;
            int2 d2 = *(const int2*)&dst[e];
            int r0 = atomicAdd(&deg[d2.x], 1);
            int r1 = atomicAdd(&deg[d2.y], 1);
            unsigned int c0 = (r0 < 255) ? (unsigned int)r0 : 255u;
            unsigned int c1 = (r1 < 255) ? (unsigned int)r1 : 255u;
            ((unsigned short*)rankb)[t2] = (unsigned short)(c0 | (c1 << 8));
        }
    } else if (b < RB2 + CONVB) {                     // xr = bf16(x), no deg dep
        int i0 = (b - RB2) * 256 + tid;               // float4 index
        for (int i = i0; i < N_NODES * D_FEAT / 4; i += CONVB * 256) {
            float4 v = ((const float4*)x)[i];
            uint2 o;
            o.x = f2bf(v.x) | (f2bf(v.y) << 16);
            o.y = f2bf(v.z) | (f2bf(v.w) << 16);
            xr[i] = o;
        }
    } else if (b < RB2 + CONVB + 32) {                // W1 -> B-fragment pack
        int idx  = (b - RB2 - CONVB) * 256 + tid;     // [0, 8192)
        int lane = idx & 63;
        int slot = idx >> 6;
        int t    = slot >> 2;                         // n-tile
        int ks   = slot & 3;                          // k-step
        int quad = lane >> 4;
        int n    = t * 16 + (lane & 15);
        unsigned int us[8];
#pragma unroll
        for (int j = 0; j < 8; j++) {
            int k = ks * 32 + quad * 8 + j;
            float v = (n < D_HID) ? W1[(size_t)k * D_HID + n] : 0.f;
            us[j] = f2bf(v);
        }
        uint4 p;
        p.x = us[0] | (us[1] << 16);
        p.y = us[2] | (us[3] << 16);
        p.z = us[4] | (us[5] << 16);
        p.w = us[6] | (us[7] << 16);
        ((uint4*)b_pk)[idx] = p;
    } else {                                          // pad b1 / W2 to 512
        for (int i = tid; i < 512; i += 256) {
            b1p[i] = (i < D_HID) ? b1[i] : 0.f;
            w2p[i] = (i < D_HID) ? W2[i] : 0.f;
        }
    }
}

// Atomic-free padded-CSR scatter (ushort, 1 edge/thread) + dinv = rsqrt(deg+1).
__global__ __launch_bounds__(256) void k_fill(const int* __restrict__ src,
                                              const int* __restrict__ dst,
                                              const unsigned char* __restrict__ rankb,
                                              const int* __restrict__ deg,
                                              unsigned short* __restrict__ csrp,
                                              float* __restrict__ dinv) {
    const int e = blockIdx.x * 256 + threadIdx.x;     // 800000 threads exactly
    int r = rankb[e];
    if (r < CSTRIDE)                                  // P(deg>64)~0 guard
        csrp[dst[e] * CSTRIDE + r] = (unsigned short)src[e];
    if (e < N_NODES)
        dinv[e] = rsqrtf((float)(deg[e] + 1));
}

// Fused gather + bf16-MFMA MLP. Block = 16 nodes, 4 waves. Gather is
// QUARTER-WAVE-PER-NODE: 16 lanes own one node; lane p holds 16B of the row;
// 4-edge unroll -> 4 independent row loads in flight per quarter. Per-edge
// dinv[s] is a same-address broadcast load (200KB, L2-hot), hidden under the
// ~900cy row-miss window; add8 -> fma8 is VALU-count-neutral (R15-17).
__global__ __launch_bounds__(256, 8) void k_gcn1(const uint4* __restrict__ xd4,
                                                 const unsigned short* __restrict__ csrp,
                                                 const int* __restrict__ deg,
                                                 const float* __restrict__ dinv,
                                                 const unsigned short* __restrict__ b_pk,
                                                 const float* __restrict__ b1p,
                                                 const float* __restrict__ w2p,
                                                 float* __restrict__ zd) {
    __shared__ unsigned short A[16][136];   // bf16 rows; 272B stride, 2-way alias = free
    __shared__ float red[4][16];
    const int t = threadIdx.x;
    const int node0 = blockIdx.x * 16;      // 50000 = 16 * 3125
    const int wv = t >> 6, lane = t & 63;
    const int q = lane >> 4, p = lane & 15;

    // ---- Phase 1: gather; quarter q of wave wv owns node n = wv*4+q ----
    {
        const int n = wv * 4 + q;
        const int node = node0 + n;
        int dg = deg[node];
        uint4 su = xd4[(size_t)node * 16 + p];        // self-loop row, prefetched
        if (dg > CSTRIDE) dg = CSTRIDE;     // never fires; memory-safety guard
        const int base = node * CSTRIDE;
        float acc[8];
#pragma unroll
        for (int j = 0; j < 8; j++) acc[j] = 0.f;

        int e = 0;
        for (; e + 4 <= dg; e += 4) {       // 1 ushort4 index load + 4 rows in flight
            ushort4 s4 = *(const ushort4*)&csrp[base + e];
            uint4 u0 = xd4[(size_t)s4.x * 16 + p];
            uint4 u1 = xd4[(size_t)s4.y * 16 + p];
            uint4 u2 = xd4[(size_t)s4.z * 16 + p];
            uint4 u3 = xd4[(size_t)s4.w * 16 + p];
            float d0 = dinv[s4.x];
            float d1 = dinv[s4.y];
            float d2 = dinv[s4.z];
            float d3 = dinv[s4.w];
            fma8(acc, u0, d0);
            fma8(acc, u1, d1);
            fma8(acc, u2, d2);
            fma8(acc, u3, d3);
        }
        for (; e < dg; e++) {
            int s = csrp[base + e];
            uint4 u = xd4[(size_t)s * 16 + p];
            fma8(acc, u, dinv[s]);
        }

        // self-loop + finalize: A[n] = bf16( di*acc + di^2 * xr[node] )
        const float di  = rsqrtf((float)(dg + 1));
        const float di2 = di * di;
        uint4 o;
        o.x = f2bf(di * acc[0] + di2 * bf_lo(su.x)) |
              (f2bf(di * acc[1] + di2 * bf_hi(su.x)) << 16);
        o.y = f2bf(di * acc[2] + di2 * bf_lo(su.y)) |
              (f2bf(di * acc[3] + di2 * bf_hi(su.y)) << 16);
        o.z = f2bf(di * acc[4] + di2 * bf_lo(su.z)) |
              (f2bf(di * acc[5] + di2 * bf_hi(su.z)) << 16);
        o.w = f2bf(di * acc[6] + di2 * bf_lo(su.w)) |
              (f2bf(di * acc[7] + di2 * bf_hi(su.w)) << 16);
        *(uint4*)&A[n][p * 8] = o;
    }
    __syncthreads();

    // ---- Phase 2: D[16][512] via 16x16x32 bf16 MFMA; wave owns 8 n-tiles ----
    bf16x8 afr[4];
#pragma unroll
    for (int ks = 0; ks < 4; ks++)
        afr[ks] = *(const bf16x8*)&A[p][ks * 32 + q * 8];

    const bf16x8* __restrict__ bpk = (const bf16x8*)b_pk;
    f32x4 acc[8];
#pragma unroll
    for (int tt = 0; tt < 8; tt++) acc[tt] = (f32x4){0.f, 0.f, 0.f, 0.f};
#pragma unroll
    for (int tt = 0; tt < 8; tt++) {
        const int tile_n = wv * 8 + tt;
#pragma unroll
        for (int ks = 0; ks < 4; ks++) {
            bf16x8 bfr = bpk[(size_t)(tile_n * 4 + ks) * 64 + lane];
            acc[tt] = __builtin_amdgcn_mfma_f32_16x16x32_bf16(afr[ks], bfr, acc[tt], 0, 0, 0);
        }
    }

    // epilogue: zd-partial = relu(D + b1) . W2   (C/D: col=p, row=q*4+r)
    float zp[4] = {0.f, 0.f, 0.f, 0.f};
#pragma unroll
    for (int tt = 0; tt < 8; tt++) {
        const int c = (wv * 8 + tt) * 16 + p;
        const float b1v = b1p[c];
        const float w2v = w2p[c];
#pragma unroll
        for (int r = 0; r < 4; r++)
            zp[r] += fmaxf(acc[tt][r] + b1v, 0.f) * w2v;
    }
#pragma unroll
    for (int off = 1; off < 16; off <<= 1) {
#pragma unroll
        for (int r = 0; r < 4; r++) zp[r] += __shfl_xor(zp[r], off);
    }
    if (p == 0) {
#pragma unroll
        for (int r = 0; r < 4; r++) red[wv][q * 4 + r] = zp[r];
    }
    __syncthreads();
    if (t < 16) {
        int node = node0 + t;
        float zz = red[0][t] + red[1][t] + red[2][t] + red[3][t];
        zd[node] = rsqrtf((float)(deg[node] + 1)) * zz;
    }
}

// Layer-2 scalar gather: 16 lanes per node, shuffle-reduce (zd 200KB, L2-hot).
__global__ __launch_bounds__(256) void k_gz(const unsigned short* __restrict__ csrp,
                                            const int* __restrict__ deg,
                                            const float* __restrict__ zd,
                                            const float* __restrict__ b2,
                                            float* __restrict__ out) {
    const int node = blockIdx.x * 16 + (threadIdx.x >> 4);
    const int l = threadIdx.x & 15;
    int dg = deg[node];
    if (dg > CSTRIDE) dg = CSTRIDE;
    const int base = node * CSTRIDE;
    float s = 0.f;
    for (int e = l; e < dg; e += 16) s += zd[csrp[base + e]];
#pragma unroll
    for (int off = 1; off < 16; off <<= 1) s += __shfl_xor(s, off);
    if (l == 0) {
        float di = rsqrtf((float)(dg + 1));
        out[node] = di * (s + zd[node]) + b2[0];
    }
}

extern "C" void kernel_launch(void* const* d_in, const int* in_sizes, int n_in,
                              void* d_out, int out_size, void* d_ws, size_t ws_size,
                              hipStream_t stream) {
    const float* x  = (const float*)d_in[0];
    const int*   ei = (const int*)d_in[1];     // [2, E]: row 0 = src, row 1 = dst
    const float* W1 = (const float*)d_in[2];
    const float* b1 = (const float*)d_in[3];
    const float* W2 = (const float*)d_in[4];
    const float* b2 = (const float*)d_in[5];
    float* out = (float*)d_out;

    const int* src = ei;
    const int* dst = ei + N_EDGES;

    // Workspace layout (~20.7 MB).
    uint2* xr            = (uint2*)d_ws;                       // 1,600,000 uint2 (12.8 MB)
    unsigned short* b_pk = (unsigned short*)(xr + 1600000);    // 65,536 bf16 (128 KB)
    float* b1p    = (float*)(b_pk + 65536);                    // 512
    float* w2p    = b1p + 512;                                 // 512
    float* zd     = w2p + 512;                                 // 50000
    int* deg      = (int*)(zd + N_NODES);                      // 50000
    float* dinv   = (float*)(deg + N_NODES);                   // 50000
    unsigned short* csrp = (unsigned short*)(dinv + N_NODES);  // 3,200,000 u16 (6.4 MB)
    unsigned char* rankb = (unsigned char*)(csrp + 3200000);   // 800,000 B

    hipMemsetAsync(deg, 0, N_NODES * sizeof(int), stream);

    k_build<<<RB2 + CONVB + 33, 256, 0, stream>>>(dst, x, W1, b1, W2, deg,
                                                  rankb, xr, b_pk, b1p, w2p);
    k_fill<<<NTILES, 256, 0, stream>>>(src, dst, rankb, deg, csrp, dinv);
    k_gcn1<<<NTILES, 256, 0, stream>>>((const uint4*)xr, csrp, deg, dinv,
                                       b_pk, b1p, w2p, zd);
    k_gz  <<<NTILES, 256, 0, stream>>>(csrp, deg, zd, b2, out);
}

// Round 2
// 173.135 us; speedup vs baseline: 1.0567x; 1.0567x over previous
//
#include <hip/hip_runtime.h>

// 2-layer GCN, padded-CSR gather + bf16-MFMA, 5 stream-ordered dispatches.
//
// LESSON (R6-R8, measured): grid.sync() costs ~250-300us EACH on MI355X.
// Do NOT fuse phases with grid.sync.
// LESSON (R9): mean degree 16 -- hide gather latency via INDEPENDENT chains
// (quarter-wave-per-node), not unroll depth.
// LESSON (R12): padded CSR (64 slots/node) kills the prefix scan.
// LESSON (R13/R14): (256,8) on k_gcn1 helps; scatter fused into the atomic
// pass regresses (random 4B stores + addr-dependency on atomic return).
// LESSON (R15-R17, measured): k_gcn1 pinned ~46.5us by the random-gather
// path -- insensitive to occupancy (41->64%), per-edge VALU work, and index
// width. 84MB HBM-side of 205MB logical = ~41% L2 miss, structural for a
// 12.8MB working set vs 4MB/XCD L2 on a random graph.
// LESSON (R18, measured): raising TLP on build phases is neutral -> atomic
// pass is ATOMIC-THROUGHPUT-bound, not latency-bound.
// LESSON (R19, measured): per-edge dinv[s] loads in k_gcn1 cost +11.4MB
// FETCH (row stream thrashes L2, dinv NOT resident) and the k_build-written
// xr pays a 12.7MB lazy writeback DURING k_gcn1: 46.8 -> 52.4us. Pre-scaled
// rows (xd = bf16(dinv*x)) are the right form for the gather kernel.
// R20: kill the device-atomic rank pass entirely. 64 blocks x 12500 edges:
// per-block LDS histogram (50K bins packed 2xu16 in 25K u32 words = 100KB);
// ds_add_rtn return value IS the local rank (~0.3us of LDS atomics vs
// ~50us of device atomics). k_scan turns counts into per-block offsets
// (in-place) + deg. No memset, no rank array, deg->xd dependency gone.
//
//   k_hist : 64 LDS-histogram blocks (lrank[e] = local rank, counts -> coff)
//            | W1 -> bf16 B-fragment pack | b1/W2 pad
//   k_scan : offs[b][n] = prefix over blocks (in-place on coff), deg[n]
//   k_fill : csrp[dst*64 + coff[b][dst]+lrank[e]] = (u16)src, 1 edge/thread
//            | xd = bf16(rsqrt(deg+1)*x) grid-stride (R18 numerics)
//   k_gcn1 : per 16-node tile: gather A[n]=dinv_n*(sum xd[s] + xd[n]) -> LDS,
//            zd = dinv * ( relu(A@W1 + b1) @ W2 ) via mfma_f32_16x16x32_bf16
//   k_gz   : out[i] = dinv[i]*(sum_{s in N(i)} zd[s] + zd[i]) + b2

#define N_NODES 50000
#define N_EDGES 800000
#define D_FEAT  128
#define D_HID   500
#define NTILES  3125         // 50000 / 16
#define BHIST   64           // histogram blocks
#define EPB     12500        // edges per histogram block (64 * 12500 = 800000)
#define CSTRIDE 64           // padded CSR slots per node

typedef __bf16 bf16x8 __attribute__((ext_vector_type(8)));
typedef float  f32x4  __attribute__((ext_vector_type(4)));

static __device__ inline unsigned int f2bf(float f) {   // fp32 -> bf16 bits, RTNE
    unsigned int u = __float_as_uint(f);
    return (u + 0x7fffu + ((u >> 16) & 1u)) >> 16;
}
static __device__ inline float bf_lo(unsigned int u) { return __uint_as_float(u << 16); }
static __device__ inline float bf_hi(unsigned int u) { return __uint_as_float(u & 0xffff0000u); }

static __device__ inline void add8(float* acc, uint4 u) {
    acc[0] += bf_lo(u.x);
    acc[1] += bf_hi(u.x);
    acc[2] += bf_lo(u.y);
    acc[3] += bf_hi(u.y);
    acc[4] += bf_lo(u.z);
    acc[5] += bf_hi(u.z);
    acc[6] += bf_lo(u.w);
    acc[7] += bf_hi(u.w);
}

// ---- k_hist: [0,BHIST) LDS-histogram rank | 32 W1-pack blocks | 1 pad ----
__global__ __launch_bounds__(256) void k_hist(const int* __restrict__ dst,
                                              const float* __restrict__ W1,
                                              const float* __restrict__ b1,
                                              const float* __restrict__ W2,
                                              unsigned short* __restrict__ coff,
                                              unsigned short* __restrict__ lrank,
                                              unsigned short* __restrict__ b_pk,
                                              float* __restrict__ b1p,
                                              float* __restrict__ w2p) {
    __shared__ unsigned int hist[N_NODES / 2];        // 25000 words = 100 KB
    const int b = blockIdx.x, tid = threadIdx.x;
    if (b < BHIST) {                                  // histogram + local rank
        for (int w = tid; w < N_NODES / 2; w += 256) hist[w] = 0u;
        __syncthreads();
        const int base = b * EPB;
        for (int i = tid; i < EPB; i += 256) {        // ~49 edges/thread
            int d = dst[base + i];
            unsigned int sh = (unsigned int)(d & 1) * 16u;
            unsigned int old = atomicAdd(&hist[d >> 1], 1u << sh);
            lrank[base + i] = (unsigned short)((old >> sh) & 0xffffu);
        }
        __syncthreads();
        unsigned int* crow = (unsigned int*)coff + (size_t)b * (N_NODES / 2);
        for (int w = tid; w < N_NODES / 2; w += 256) crow[w] = hist[w];
    } else if (b < BHIST + 32) {                      // W1 -> B-fragment pack
        int idx  = (b - BHIST) * 256 + tid;           // [0, 8192)
        int lane = idx & 63;
        int slot = idx >> 6;
        int t    = slot >> 2;                         // n-tile
        int ks   = slot & 3;                          // k-step
        int quad = lane >> 4;
        int n    = t * 16 + (lane & 15);
        unsigned int us[8];
#pragma unroll
        for (int j = 0; j < 8; j++) {
            int k = ks * 32 + quad * 8 + j;
            float v = (n < D_HID) ? W1[(size_t)k * D_HID + n] : 0.f;
            us[j] = f2bf(v);
        }
        uint4 p;
        p.x = us[0] | (us[1] << 16);
        p.y = us[2] | (us[3] << 16);
        p.z = us[4] | (us[5] << 16);
        p.w = us[6] | (us[7] << 16);
        ((uint4*)b_pk)[idx] = p;
    } else {                                          // pad b1 / W2 to 512
        for (int i = tid; i < 512; i += 256) {
            b1p[i] = (i < D_HID) ? b1[i] : 0.f;
            w2p[i] = (i < D_HID) ? W2[i] : 0.f;
        }
    }
}

// Per-node prefix over the 64 block-counts (in-place: coff becomes offsets),
// deg[n] = total. Wave accesses are contiguous per b-step (coalesced).
__global__ __launch_bounds__(256) void k_scan(unsigned short* __restrict__ coff,
                                              int* __restrict__ deg) {
    const int n = blockIdx.x * 256 + threadIdx.x;
    if (n >= N_NODES) return;
    int run = 0;
#pragma unroll 8
    for (int b = 0; b < BHIST; b++) {
        size_t idx = (size_t)b * N_NODES + n;
        int c = coff[idx];
        coff[idx] = (unsigned short)run;
        run += c;
    }
    deg[n] = run;
}

// Padded-CSR scatter (rank = block-offset + local rank) + xd = bf16(dinv*x).
__global__ __launch_bounds__(256) void k_fill(const int* __restrict__ src,
                                              const int* __restrict__ dst,
                                              const unsigned short* __restrict__ coff,
                                              const unsigned short* __restrict__ lrank,
                                              const int* __restrict__ deg,
                                              const float* __restrict__ x,
                                              unsigned short* __restrict__ csrp,
                                              uint2* __restrict__ xd) {
    const int e = blockIdx.x * 256 + threadIdx.x;     // 800000 threads exactly
    {
        int d = dst[e];
        int b = e / EPB;                              // magic-mul div
        int r = (int)coff[(size_t)b * N_NODES + d] + (int)lrank[e];
        if (r < CSTRIDE)                              // P(deg>64)~0 guard
            csrp[d * CSTRIDE + r] = (unsigned short)src[e];
    }
    // convert 1,600,000 float4 (deg final; L2-hot broadcast), 2 iters/thread
    for (int i = e; i < N_NODES * D_FEAT / 4; i += N_EDGES) {
        float dv = rsqrtf((float)(deg[i >> 5] + 1));  // 32 float4 per node row
        float4 v = ((const float4*)x)[i];
        uint2 o;
        o.x = f2bf(dv * v.x) | (f2bf(dv * v.y) << 16);
        o.y = f2bf(dv * v.z) | (f2bf(dv * v.w) << 16);
        xd[i] = o;
    }
}

// Fused gather + bf16-MFMA MLP. Block = 16 nodes, 4 waves. Gather is
// QUARTER-WAVE-PER-NODE: 16 lanes own one node; lane p holds 16B of the row;
// 4-edge unroll -> 4 independent row loads in flight per quarter. Inner loop
// is pure index->row->add; indices are ushort (one 8B load per 4 edges).
__global__ __launch_bounds__(256, 8) void k_gcn1(const uint4* __restrict__ xd4,
                                                 const unsigned short* __restrict__ csrp,
                                                 const int* __restrict__ deg,
                                                 const unsigned short* __restrict__ b_pk,
                                                 const float* __restrict__ b1p,
                                                 const float* __restrict__ w2p,
                                                 float* __restrict__ zd) {
    __shared__ unsigned short A[16][136];   // bf16 rows; 272B stride, 2-way alias = free
    __shared__ float red[4][16];
    const int t = threadIdx.x;
    const int node0 = blockIdx.x * 16;      // 50000 = 16 * 3125
    const int wv = t >> 6, lane = t & 63;
    const int q = lane >> 4, p = lane & 15;

    // ---- Phase 1: gather; quarter q of wave wv owns node n = wv*4+q ----
    {
        const int n = wv * 4 + q;
        const int node = node0 + n;
        int dg = deg[node];
        uint4 su = xd4[(size_t)node * 16 + p];        // self-loop row, prefetched
        if (dg > CSTRIDE) dg = CSTRIDE;     // never fires; memory-safety guard
        const int base = node * CSTRIDE;
        float acc[8];
#pragma unroll
        for (int j = 0; j < 8; j++) acc[j] = 0.f;

        int e = 0;
        for (; e + 4 <= dg; e += 4) {       // 1 ushort4 index load + 4 rows in flight
            ushort4 s4 = *(const ushort4*)&csrp[base + e];
            uint4 u0 = xd4[(size_t)s4.x * 16 + p];
            uint4 u1 = xd4[(size_t)s4.y * 16 + p];
            uint4 u2 = xd4[(size_t)s4.z * 16 + p];
            uint4 u3 = xd4[(size_t)s4.w * 16 + p];
            add8(acc, u0);
            add8(acc, u1);
            add8(acc, u2);
            add8(acc, u3);
        }
        for (; e < dg; e++) {
            int s = csrp[base + e];
            uint4 u = xd4[(size_t)s * 16 + p];
            add8(acc, u);
        }

        // self-loop + finalize: A[n] = bf16( di * (acc + xd[node]) )
        const float di = rsqrtf((float)(dg + 1));
        uint4 o;
        o.x = f2bf(di * (acc[0] + bf_lo(su.x))) |
              (f2bf(di * (acc[1] + bf_hi(su.x))) << 16);
        o.y = f2bf(di * (acc[2] + bf_lo(su.y))) |
              (f2bf(di * (acc[3] + bf_hi(su.y))) << 16);
        o.z = f2bf(di * (acc[4] + bf_lo(su.z))) |
              (f2bf(di * (acc[5] + bf_hi(su.z))) << 16);
        o.w = f2bf(di * (acc[6] + bf_lo(su.w))) |
              (f2bf(di * (acc[7] + bf_hi(su.w))) << 16);
        *(uint4*)&A[n][p * 8] = o;
    }
    __syncthreads();

    // ---- Phase 2: D[16][512] via 16x16x32 bf16 MFMA; wave owns 8 n-tiles ----
    bf16x8 afr[4];
#pragma unroll
    for (int ks = 0; ks < 4; ks++)
        afr[ks] = *(const bf16x8*)&A[p][ks * 32 + q * 8];

    const bf16x8* __restrict__ bpk = (const bf16x8*)b_pk;
    f32x4 acc[8];
#pragma unroll
    for (int tt = 0; tt < 8; tt++) acc[tt] = (f32x4){0.f, 0.f, 0.f, 0.f};
#pragma unroll
    for (int tt = 0; tt < 8; tt++) {
        const int tile_n = wv * 8 + tt;
#pragma unroll
        for (int ks = 0; ks < 4; ks++) {
            bf16x8 bfr = bpk[(size_t)(tile_n * 4 + ks) * 64 + lane];
            acc[tt] = __builtin_amdgcn_mfma_f32_16x16x32_bf16(afr[ks], bfr, acc[tt], 0, 0, 0);
        }
    }

    // epilogue: zd-partial = relu(D + b1) . W2   (C/D: col=p, row=q*4+r)
    float zp[4] = {0.f, 0.f, 0.f, 0.f};
#pragma unroll
    for (int tt = 0; tt < 8; tt++) {
        const int c = (wv * 8 + tt) * 16 + p;
        const float b1v = b1p[c];
        const float w2v = w2p[c];
#pragma unroll
        for (int r = 0; r < 4; r++)
            zp[r] += fmaxf(acc[tt][r] + b1v, 0.f) * w2v;
    }
#pragma unroll
    for (int off = 1; off < 16; off <<= 1) {
#pragma unroll
        for (int r = 0; r < 4; r++) zp[r] += __shfl_xor(zp[r], off);
    }
    if (p == 0) {
#pragma unroll
        for (int r = 0; r < 4; r++) red[wv][q * 4 + r] = zp[r];
    }
    __syncthreads();
    if (t < 16) {
        int node = node0 + t;
        float zz = red[0][t] + red[1][t] + red[2][t] + red[3][t];
        zd[node] = rsqrtf((float)(deg[node] + 1)) * zz;
    }
}

// Layer-2 scalar gather: 16 lanes per node, shuffle-reduce (zd 200KB, L2-hot).
__global__ __launch_bounds__(256) void k_gz(const unsigned short* __restrict__ csrp,
                                            const int* __restrict__ deg,
                                            const float* __restrict__ zd,
                                            const float* __restrict__ b2,
                                            float* __restrict__ out) {
    const int node = blockIdx.x * 16 + (threadIdx.x >> 4);
    const int l = threadIdx.x & 15;
    int dg = deg[node];
    if (dg > CSTRIDE) dg = CSTRIDE;
    const int base = node * CSTRIDE;
    float s = 0.f;
    for (int e = l; e < dg; e += 16) s += zd[csrp[base + e]];
#pragma unroll
    for (int off = 1; off < 16; off <<= 1) s += __shfl_xor(s, off);
    if (l == 0) {
        float di = rsqrtf((float)(dg + 1));
        out[node] = di * (s + zd[node]) + b2[0];
    }
}

extern "C" void kernel_launch(void* const* d_in, const int* in_sizes, int n_in,
                              void* d_out, int out_size, void* d_ws, size_t ws_size,
                              hipStream_t stream) {
    const float* x  = (const float*)d_in[0];
    const int*   ei = (const int*)d_in[1];     // [2, E]: row 0 = src, row 1 = dst
    const float* W1 = (const float*)d_in[2];
    const float* b1 = (const float*)d_in[3];
    const float* W2 = (const float*)d_in[4];
    const float* b2 = (const float*)d_in[5];
    float* out = (float*)d_out;

    const int* src = ei;
    const int* dst = ei + N_EDGES;

    // Workspace layout (~27.7 MB).
    uint2* xd            = (uint2*)d_ws;                       // 1,600,000 uint2 (12.8 MB)
    unsigned short* b_pk = (unsigned short*)(xd + 1600000);    // 65,536 bf16 (128 KB)
    float* b1p    = (float*)(b_pk + 65536);                    // 512
    float* w2p    = b1p + 512;                                 // 512
    float* zd     = w2p + 512;                                 // 50000
    int* deg      = (int*)(zd + N_NODES);                      // 50000
    unsigned short* coff  = (unsigned short*)(deg + N_NODES);  // 64*50000 u16 (6.4 MB)
    unsigned short* lrank = coff + (size_t)BHIST * N_NODES;    // 800,000 u16 (1.6 MB)
    unsigned short* csrp  = lrank + N_EDGES;                   // 3,200,000 u16 (6.4 MB)

    k_hist<<<BHIST + 33, 256, 0, stream>>>(dst, W1, b1, W2, coff, lrank,
                                           b_pk, b1p, w2p);
    k_scan<<<(N_NODES + 255) / 256, 256, 0, stream>>>(coff, deg);
    k_fill<<<NTILES, 256, 0, stream>>>(src, dst, coff, lrank, deg, x, csrp, xd);
    k_gcn1<<<NTILES, 256, 0, stream>>>((const uint4*)xd, csrp, deg,
                                       b_pk, b1p, w2p, zd);
    k_gz  <<<NTILES, 256, 0, stream>>>(csrp, deg, zd, b2, out);
}

// Round 3
// 160.930 us; speedup vs baseline: 1.1368x; 1.0758x over previous
//
#include <hip/hip_runtime.h>

// 2-layer GCN, padded-CSR gather + bf16-MFMA, 5 stream-ordered dispatches.
//
// LESSON (R6-R8, measured): grid.sync() costs ~250-300us EACH on MI355X.
// Do NOT fuse phases with grid.sync.
// LESSON (R9): mean degree 16 -- hide gather latency via INDEPENDENT chains
// (quarter-wave-per-node), not unroll depth.
// LESSON (R12): padded CSR (64 slots/node) kills the prefix scan.
// LESSON (R13/R14): (256,8) on k_gcn1 helps; scatter fused into the atomic
// pass regresses (random 4B stores + addr-dependency on atomic return).
// LESSON (R15-R17, measured): k_gcn1 pinned ~46.5us by the random-gather
// path -- insensitive to occupancy (41->64%), per-edge VALU work, and index
// width. 84MB HBM-side of 205MB logical = ~41% L2 miss, structural for a
// 12.8MB working set vs 4MB/XCD L2 on a random graph.
// LESSON (R18, measured): raising TLP on build phases is neutral.
// LESSON (R19, measured): per-edge dinv[s] loads in k_gcn1 cost +11.4MB
// FETCH (row stream thrashes L2, dinv NOT resident) and k_build-written xr
// pays a 12.7MB lazy writeback DURING k_gcn1: 46.8 -> 52.4us. Pre-scaled
// rows (xd = bf16(dinv*x)) are the right form for the gather kernel.
// LESSON (R20, measured): LDS-histogram rank beats 800K device atomics:
// 180 -> 173us total, k_gcn1 restored to 47.0us / 84.5MB FETCH / 0.2MB
// WRITE. But the atomic pass was NOT a ~50us sink; ~126us remains outside
// k_gcn1 (hist/scan/fill/gz + launch overhead, each <46.5us).
// R21: k_hist ran 64 blocks x 256thr x 100KB LDS = 1 wave/SIMD on 64 CUs --
// worst-case latency exposure on its 49-deep {load,ds_atomic,store} loop.
// Now 1024 thr/block (16 waves/CU) + int4 edge loads (4 indep chains, ~3
// iters); W1-pack/pad blocks ride in the same grid on the idle 192 CUs.
// k_fill goes 2 edges/thread (int2 index loads).
//
//   k_hist : 64 LDS-histogram blocks @1024thr (lrank = local rank, counts)
//            | 8 W1-pack blocks | 1 pad block (idle CUs, overlapped)
//   k_scan : coff[b][n] -> prefix over blocks (in-place), deg[n] = total
//   k_fill : csrp[dst*64 + coff[b][dst]+lrank[e]] = (u16)src, 2 edges/thread
//            | xd = bf16(rsqrt(deg+1)*x) grid-stride
//   k_gcn1 : per 16-node tile: gather A[n]=dinv_n*(sum xd[s] + xd[n]) -> LDS,
//            zd = dinv * ( relu(A@W1 + b1) @ W2 ) via mfma_f32_16x16x32_bf16
//   k_gz   : out[i] = dinv[i]*(sum_{s in N(i)} zd[s] + zd[i]) + b2

#define N_NODES 50000
#define N_EDGES 800000
#define D_FEAT  128
#define D_HID   500
#define NTILES  3125         // 50000 / 16
#define BHIST   64           // histogram blocks
#define EPB     12500        // edges per histogram block (64 * 12500 = 800000)
#define FB      1563         // fill blocks: ceil(400000 / 256)
#define CSTRIDE 64           // padded CSR slots per node

typedef __bf16 bf16x8 __attribute__((ext_vector_type(8)));
typedef float  f32x4  __attribute__((ext_vector_type(4)));

static __device__ inline unsigned int f2bf(float f) {   // fp32 -> bf16 bits, RTNE
    unsigned int u = __float_as_uint(f);
    return (u + 0x7fffu + ((u >> 16) & 1u)) >> 16;
}
static __device__ inline float bf_lo(unsigned int u) { return __uint_as_float(u << 16); }
static __device__ inline float bf_hi(unsigned int u) { return __uint_as_float(u & 0xffff0000u); }

static __device__ inline void add8(float* acc, uint4 u) {
    acc[0] += bf_lo(u.x);
    acc[1] += bf_hi(u.x);
    acc[2] += bf_lo(u.y);
    acc[3] += bf_hi(u.y);
    acc[4] += bf_lo(u.z);
    acc[5] += bf_hi(u.z);
    acc[6] += bf_lo(u.w);
    acc[7] += bf_hi(u.w);
}

// ---- k_hist: [0,BHIST) LDS-histogram rank @1024thr | 8 W1-pack | 1 pad ----
__global__ __launch_bounds__(1024) void k_hist(const int* __restrict__ dst,
                                               const float* __restrict__ W1,
                                               const float* __restrict__ b1,
                                               const float* __restrict__ W2,
                                               unsigned short* __restrict__ coff,
                                               unsigned short* __restrict__ lrank,
                                               unsigned short* __restrict__ b_pk,
                                               float* __restrict__ b1p,
                                               float* __restrict__ w2p) {
    __shared__ unsigned int hist[N_NODES / 2];        // 25000 words = 100 KB
    const int b = blockIdx.x, tid = threadIdx.x;
    if (b < BHIST) {                                  // histogram + local rank
        for (int w = tid; w < N_NODES / 2; w += 1024) hist[w] = 0u;
        __syncthreads();
        const int base = b * EPB;
        for (int i = tid * 4; i < EPB; i += 4096) {   // 4 indep atomic chains
            int4 d4 = *(const int4*)&dst[base + i];
            unsigned int s0 = (unsigned int)(d4.x & 1) * 16u;
            unsigned int s1 = (unsigned int)(d4.y & 1) * 16u;
            unsigned int s2 = (unsigned int)(d4.z & 1) * 16u;
            unsigned int s3 = (unsigned int)(d4.w & 1) * 16u;
            unsigned int r0 = atomicAdd(&hist[d4.x >> 1], 1u << s0);
            unsigned int r1 = atomicAdd(&hist[d4.y >> 1], 1u << s1);
            unsigned int r2 = atomicAdd(&hist[d4.z >> 1], 1u << s2);
            unsigned int r3 = atomicAdd(&hist[d4.w >> 1], 1u << s3);
            ushort4 lr;
            lr.x = (unsigned short)((r0 >> s0) & 0xffffu);
            lr.y = (unsigned short)((r1 >> s1) & 0xffffu);
            lr.z = (unsigned short)((r2 >> s2) & 0xffffu);
            lr.w = (unsigned short)((r3 >> s3) & 0xffffu);
            *(ushort4*)&lrank[base + i] = lr;
        }
        __syncthreads();
        unsigned int* crow = (unsigned int*)coff + (size_t)b * (N_NODES / 2);
        for (int w = tid; w < N_NODES / 2; w += 1024) crow[w] = hist[w];
    } else if (b < BHIST + 8) {                       // W1 -> B-fragment pack
        int idx  = (b - BHIST) * 1024 + tid;          // [0, 8192)
        int lane = idx & 63;
        int slot = idx >> 6;
        int t    = slot >> 2;                         // n-tile
        int ks   = slot & 3;                          // k-step
        int quad = lane >> 4;
        int n    = t * 16 + (lane & 15);
        unsigned int us[8];
#pragma unroll
        for (int j = 0; j < 8; j++) {
            int k = ks * 32 + quad * 8 + j;
            float v = (n < D_HID) ? W1[(size_t)k * D_HID + n] : 0.f;
            us[j] = f2bf(v);
        }
        uint4 p;
        p.x = us[0] | (us[1] << 16);
        p.y = us[2] | (us[3] << 16);
        p.z = us[4] | (us[5] << 16);
        p.w = us[6] | (us[7] << 16);
        ((uint4*)b_pk)[idx] = p;
    } else {                                          // pad b1 / W2 to 512
        if (tid < 512) {
            b1p[tid] = (tid < D_HID) ? b1[tid] : 0.f;
            w2p[tid] = (tid < D_HID) ? W2[tid] : 0.f;
        }
    }
}

// Per-node prefix over the 64 block-counts (in-place: coff becomes offsets),
// deg[n] = total. Wave accesses are contiguous per b-step (coalesced).
__global__ __launch_bounds__(256) void k_scan(unsigned short* __restrict__ coff,
                                              int* __restrict__ deg) {
    const int n = blockIdx.x * 256 + threadIdx.x;
    if (n >= N_NODES) return;
    int run = 0;
#pragma unroll 8
    for (int b = 0; b < BHIST; b++) {
        size_t idx = (size_t)b * N_NODES + n;
        int c = coff[idx];
        coff[idx] = (unsigned short)run;
        run += c;
    }
    deg[n] = run;
}

// Padded-CSR scatter (rank = block-offset + local rank), 2 edges/thread,
// + xd = bf16(dinv*x) grid-stride conversion.
__global__ __launch_bounds__(256) void k_fill(const int* __restrict__ src,
                                              const int* __restrict__ dst,
                                              const unsigned short* __restrict__ coff,
                                              const unsigned short* __restrict__ lrank,
                                              const int* __restrict__ deg,
                                              const float* __restrict__ x,
                                              unsigned short* __restrict__ csrp,
                                              uint2* __restrict__ xd) {
    const int gid = blockIdx.x * 256 + threadIdx.x;
    if (gid < N_EDGES / 2) {
        const int e = gid * 2;
        int2 s2 = *(const int2*)&src[e];
        int2 d2 = *(const int2*)&dst[e];
        ushort2 lr = *(const ushort2*)&lrank[e];
        int b0 = e / EPB;                             // magic-mul div
        int b1 = (e + 1) / EPB;
        int r0 = (int)coff[(size_t)b0 * N_NODES + d2.x] + (int)lr.x;
        int r1 = (int)coff[(size_t)b1 * N_NODES + d2.y] + (int)lr.y;
        if (r0 < CSTRIDE) csrp[d2.x * CSTRIDE + r0] = (unsigned short)s2.x;
        if (r1 < CSTRIDE) csrp[d2.y * CSTRIDE + r1] = (unsigned short)s2.y;
    }
    // convert 1,600,000 float4 (deg final; L2-hot broadcast), 4 iters/thread
    for (int i = gid; i < N_NODES * D_FEAT / 4; i += FB * 256) {
        float dv = rsqrtf((float)(deg[i >> 5] + 1));  // 32 float4 per node row
        float4 v = ((const float4*)x)[i];
        uint2 o;
        o.x = f2bf(dv * v.x) | (f2bf(dv * v.y) << 16);
        o.y = f2bf(dv * v.z) | (f2bf(dv * v.w) << 16);
        xd[i] = o;
    }
}

// Fused gather + bf16-MFMA MLP. Block = 16 nodes, 4 waves. Gather is
// QUARTER-WAVE-PER-NODE: 16 lanes own one node; lane p holds 16B of the row;
// 4-edge unroll -> 4 independent row loads in flight per quarter. Inner loop
// is pure index->row->add; indices are ushort (one 8B load per 4 edges).
__global__ __launch_bounds__(256, 8) void k_gcn1(const uint4* __restrict__ xd4,
                                                 const unsigned short* __restrict__ csrp,
                                                 const int* __restrict__ deg,
                                                 const unsigned short* __restrict__ b_pk,
                                                 const float* __restrict__ b1p,
                                                 const float* __restrict__ w2p,
                                                 float* __restrict__ zd) {
    __shared__ unsigned short A[16][136];   // bf16 rows; 272B stride, 2-way alias = free
    __shared__ float red[4][16];
    const int t = threadIdx.x;
    const int node0 = blockIdx.x * 16;      // 50000 = 16 * 3125
    const int wv = t >> 6, lane = t & 63;
    const int q = lane >> 4, p = lane & 15;

    // ---- Phase 1: gather; quarter q of wave wv owns node n = wv*4+q ----
    {
        const int n = wv * 4 + q;
        const int node = node0 + n;
        int dg = deg[node];
        uint4 su = xd4[(size_t)node * 16 + p];        // self-loop row, prefetched
        if (dg > CSTRIDE) dg = CSTRIDE;     // never fires; memory-safety guard
        const int base = node * CSTRIDE;
        float acc[8];
#pragma unroll
        for (int j = 0; j < 8; j++) acc[j] = 0.f;

        int e = 0;
        for (; e + 4 <= dg; e += 4) {       // 1 ushort4 index load + 4 rows in flight
            ushort4 s4 = *(const ushort4*)&csrp[base + e];
            uint4 u0 = xd4[(size_t)s4.x * 16 + p];
            uint4 u1 = xd4[(size_t)s4.y * 16 + p];
            uint4 u2 = xd4[(size_t)s4.z * 16 + p];
            uint4 u3 = xd4[(size_t)s4.w * 16 + p];
            add8(acc, u0);
            add8(acc, u1);
            add8(acc, u2);
            add8(acc, u3);
        }
        for (; e < dg; e++) {
            int s = csrp[base + e];
            uint4 u = xd4[(size_t)s * 16 + p];
            add8(acc, u);
        }

        // self-loop + finalize: A[n] = bf16( di * (acc + xd[node]) )
        const float di = rsqrtf((float)(dg + 1));
        uint4 o;
        o.x = f2bf(di * (acc[0] + bf_lo(su.x))) |
              (f2bf(di * (acc[1] + bf_hi(su.x))) << 16);
        o.y = f2bf(di * (acc[2] + bf_lo(su.y))) |
              (f2bf(di * (acc[3] + bf_hi(su.y))) << 16);
        o.z = f2bf(di * (acc[4] + bf_lo(su.z))) |
              (f2bf(di * (acc[5] + bf_hi(su.z))) << 16);
        o.w = f2bf(di * (acc[6] + bf_lo(su.w))) |
              (f2bf(di * (acc[7] + bf_hi(su.w))) << 16);
        *(uint4*)&A[n][p * 8] = o;
    }
    __syncthreads();

    // ---- Phase 2: D[16][512] via 16x16x32 bf16 MFMA; wave owns 8 n-tiles ----
    bf16x8 afr[4];
#pragma unroll
    for (int ks = 0; ks < 4; ks++)
        afr[ks] = *(const bf16x8*)&A[p][ks * 32 + q * 8];

    const bf16x8* __restrict__ bpk = (const bf16x8*)b_pk;
    f32x4 acc[8];
#pragma unroll
    for (int tt = 0; tt < 8; tt++) acc[tt] = (f32x4){0.f, 0.f, 0.f, 0.f};
#pragma unroll
    for (int tt = 0; tt < 8; tt++) {
        const int tile_n = wv * 8 + tt;
#pragma unroll
        for (int ks = 0; ks < 4; ks++) {
            bf16x8 bfr = bpk[(size_t)(tile_n * 4 + ks) * 64 + lane];
            acc[tt] = __builtin_amdgcn_mfma_f32_16x16x32_bf16(afr[ks], bfr, acc[tt], 0, 0, 0);
        }
    }

    // epilogue: zd-partial = relu(D + b1) . W2   (C/D: col=p, row=q*4+r)
    float zp[4] = {0.f, 0.f, 0.f, 0.f};
#pragma unroll
    for (int tt = 0; tt < 8; tt++) {
        const int c = (wv * 8 + tt) * 16 + p;
        const float b1v = b1p[c];
        const float w2v = w2p[c];
#pragma unroll
        for (int r = 0; r < 4; r++)
            zp[r] += fmaxf(acc[tt][r] + b1v, 0.f) * w2v;
    }
#pragma unroll
    for (int off = 1; off < 16; off <<= 1) {
#pragma unroll
        for (int r = 0; r < 4; r++) zp[r] += __shfl_xor(zp[r], off);
    }
    if (p == 0) {
#pragma unroll
        for (int r = 0; r < 4; r++) red[wv][q * 4 + r] = zp[r];
    }
    __syncthreads();
    if (t < 16) {
        int node = node0 + t;
        float zz = red[0][t] + red[1][t] + red[2][t] + red[3][t];
        zd[node] = rsqrtf((float)(deg[node] + 1)) * zz;
    }
}

// Layer-2 scalar gather: 16 lanes per node, shuffle-reduce (zd 200KB, L2-hot).
__global__ __launch_bounds__(256) void k_gz(const unsigned short* __restrict__ csrp,
                                            const int* __restrict__ deg,
                                            const float* __restrict__ zd,
                                            const float* __restrict__ b2,
                                            float* __restrict__ out) {
    const int node = blockIdx.x * 16 + (threadIdx.x >> 4);
    const int l = threadIdx.x & 15;
    int dg = deg[node];
    if (dg > CSTRIDE) dg = CSTRIDE;
    const int base = node * CSTRIDE;
    float s = 0.f;
    for (int e = l; e < dg; e += 16) s += zd[csrp[base + e]];
#pragma unroll
    for (int off = 1; off < 16; off <<= 1) s += __shfl_xor(s, off);
    if (l == 0) {
        float di = rsqrtf((float)(dg + 1));
        out[node] = di * (s + zd[node]) + b2[0];
    }
}

extern "C" void kernel_launch(void* const* d_in, const int* in_sizes, int n_in,
                              void* d_out, int out_size, void* d_ws, size_t ws_size,
                              hipStream_t stream) {
    const float* x  = (const float*)d_in[0];
    const int*   ei = (const int*)d_in[1];     // [2, E]: row 0 = src, row 1 = dst
    const float* W1 = (const float*)d_in[2];
    const float* b1 = (const float*)d_in[3];
    const float* W2 = (const float*)d_in[4];
    const float* b2 = (const float*)d_in[5];
    float* out = (float*)d_out;

    const int* src = ei;
    const int* dst = ei + N_EDGES;

    // Workspace layout (~27.7 MB).
    uint2* xd            = (uint2*)d_ws;                       // 1,600,000 uint2 (12.8 MB)
    unsigned short* b_pk = (unsigned short*)(xd + 1600000);    // 65,536 bf16 (128 KB)
    float* b1p    = (float*)(b_pk + 65536);                    // 512
    float* w2p    = b1p + 512;                                 // 512
    float* zd     = w2p + 512;                                 // 50000
    int* deg      = (int*)(zd + N_NODES);                      // 50000
    unsigned short* coff  = (unsigned short*)(deg + N_NODES);  // 64*50000 u16 (6.4 MB)
    unsigned short* lrank = coff + (size_t)BHIST * N_NODES;    // 800,000 u16 (1.6 MB)
    unsigned short* csrp  = lrank + N_EDGES;                   // 3,200,000 u16 (6.4 MB)

    k_hist<<<BHIST + 9, 1024, 0, stream>>>(dst, W1, b1, W2, coff, lrank,
                                           b_pk, b1p, w2p);
    k_scan<<<(N_NODES + 255) / 256, 256, 0, stream>>>(coff, deg);
    k_fill<<<FB, 256, 0, stream>>>(src, dst, coff, lrank, deg, x, csrp, xd);
    k_gcn1<<<NTILES, 256, 0, stream>>>((const uint4*)xd, csrp, deg,
                                       b_pk, b1p, w2p, zd);
    k_gz  <<<NTILES, 256, 0, stream>>>(csrp, deg, zd, b2, out);
}

// Round 4
// 154.047 us; speedup vs baseline: 1.1876x; 1.0447x over previous
//
#include <hip/hip_runtime.h>

// 2-layer GCN, padded-CSR gather + bf16-MFMA, 5 stream-ordered dispatches.
//
// LESSON (R6-R8, measured): grid.sync() costs ~250-300us EACH on MI355X.
// Do NOT fuse phases with grid.sync.
// LESSON (R9): mean degree 16 -- hide gather latency via INDEPENDENT chains
// (quarter-wave-per-node), not unroll depth.
// LESSON (R12): padded CSR (64 slots/node) kills the prefix scan.
// LESSON (R13/R14): (256,8) on k_gcn1 helps; scatter fused into the atomic
// pass regresses (random 4B stores + addr-dependency on atomic return).
// LESSON (R15-R17, measured): k_gcn1 pinned ~46.5us by the random-gather
// path -- insensitive to occupancy (41->64%), per-edge VALU work, and index
// width. 84MB HBM-side of 205MB logical = ~41% L2 miss, structural for a
// 12.8MB working set vs 4MB/XCD L2 on a random graph.
// LESSON (R19, measured): random small-gathers into tables that miss the
// per-XCD L2 cost ~10+MB of HBM re-fetch (dinv experiment). Avoid them.
// LESSON (R20, measured): LDS-histogram rank beats 800K device atomics.
// LESSON (R21, measured): k_hist at 1 wave/SIMD was latency-bound: 1024thr
// + int4 loads = -12.2us total (173.1 -> 160.9). Occupancy on the build
// kernels matters when the loop is {load -> ds_atomic -> store}.
// R22: the remaining ~114us non-gcn1 budget is build-path traffic. (a) u8
// coff/lrank (counts <= ~45): halves hist-write/scan/fill traffic; hist LDS
// packs 4 nodes/word (50KB). (b) k_fill scatter blocks align 1:1 with hist
// blocks: block b stages its 50KB coff row in LDS (sequential) and the 800K
// RANDOM global coff gathers become LDS lookups (R19's mechanism, removed).
// (c) k_scan walks 4 nodes/u32 word (4x fewer insts, same coalescing).
//
//   k_hist : 64 LDS-histogram blocks @1024thr (u8 lrank, u8 counts)
//            | 8 W1-pack blocks | 1 pad block (idle CUs, overlapped)
//   k_scan : coff[b][n] -> prefix over blocks (in-place, 4 nodes/word),
//            deg[n] = total
//   k_fill : blocks [0,64): stage coff row b in LDS; csrp[dst*64 +
//            lcoff[dst]+lrank[e]] = (u16)src, 4 edges/thread
//            blocks [64,456): xd = bf16(rsqrt(deg+1)*x) grid-stride
//   k_gcn1 : per 16-node tile: gather A[n]=dinv_n*(sum xd[s] + xd[n]) -> LDS,
//            zd = dinv * ( relu(A@W1 + b1) @ W2 ) via mfma_f32_16x16x32_bf16
//   k_gz   : out[i] = dinv[i]*(sum_{s in N(i)} zd[s] + zd[i]) + b2

#define N_NODES 50000
#define N_EDGES 800000
#define D_FEAT  128
#define D_HID   500
#define NTILES  3125         // 50000 / 16
#define BHIST   64           // histogram blocks
#define EPB     12500        // edges per histogram block (64 * 12500 = 800000)
#define CONVB   392          // conversion blocks in k_fill (1024 thr each)
#define CSTRIDE 64           // padded CSR slots per node

typedef __bf16 bf16x8 __attribute__((ext_vector_type(8)));
typedef float  f32x4  __attribute__((ext_vector_type(4)));

static __device__ inline unsigned int f2bf(float f) {   // fp32 -> bf16 bits, RTNE
    unsigned int u = __float_as_uint(f);
    return (u + 0x7fffu + ((u >> 16) & 1u)) >> 16;
}
static __device__ inline float bf_lo(unsigned int u) { return __uint_as_float(u << 16); }
static __device__ inline float bf_hi(unsigned int u) { return __uint_as_float(u & 0xffff0000u); }

static __device__ inline void add8(float* acc, uint4 u) {
    acc[0] += bf_lo(u.x);
    acc[1] += bf_hi(u.x);
    acc[2] += bf_lo(u.y);
    acc[3] += bf_hi(u.y);
    acc[4] += bf_lo(u.z);
    acc[5] += bf_hi(u.z);
    acc[6] += bf_lo(u.w);
    acc[7] += bf_hi(u.w);
}

// ---- k_hist: [0,BHIST) LDS-histogram rank @1024thr | 8 W1-pack | 1 pad ----
// Histogram packs 4 nodes per u32 word (u8 counts; per-block per-node count
// is Poisson lambda=0.25 -- 255 is unreachable). ds_add_rtn byte IS the rank.
__global__ __launch_bounds__(1024) void k_hist(const int* __restrict__ dst,
                                               const float* __restrict__ W1,
                                               const float* __restrict__ b1,
                                               const float* __restrict__ W2,
                                               unsigned char* __restrict__ coff,
                                               unsigned char* __restrict__ lrank,
                                               unsigned short* __restrict__ b_pk,
                                               float* __restrict__ b1p,
                                               float* __restrict__ w2p) {
    __shared__ unsigned int hist[N_NODES / 4];        // 12500 words = 50 KB
    const int b = blockIdx.x, tid = threadIdx.x;
    if (b < BHIST) {                                  // histogram + local rank
        for (int w = tid; w < N_NODES / 4; w += 1024) hist[w] = 0u;
        __syncthreads();
        const int base = b * EPB;
        for (int i = tid * 4; i < EPB; i += 4096) {   // 4 indep atomic chains
            int4 d4 = *(const int4*)&dst[base + i];
            unsigned int s0 = (unsigned int)(d4.x & 3) * 8u;
            unsigned int s1 = (unsigned int)(d4.y & 3) * 8u;
            unsigned int s2 = (unsigned int)(d4.z & 3) * 8u;
            unsigned int s3 = (unsigned int)(d4.w & 3) * 8u;
            unsigned int r0 = atomicAdd(&hist[d4.x >> 2], 1u << s0);
            unsigned int r1 = atomicAdd(&hist[d4.y >> 2], 1u << s1);
            unsigned int r2 = atomicAdd(&hist[d4.z >> 2], 1u << s2);
            unsigned int r3 = atomicAdd(&hist[d4.w >> 2], 1u << s3);
            uchar4 lr;
            lr.x = (unsigned char)((r0 >> s0) & 0xffu);
            lr.y = (unsigned char)((r1 >> s1) & 0xffu);
            lr.z = (unsigned char)((r2 >> s2) & 0xffu);
            lr.w = (unsigned char)((r3 >> s3) & 0xffu);
            *(uchar4*)&lrank[base + i] = lr;
        }
        __syncthreads();
        unsigned int* crow = (unsigned int*)coff + (size_t)b * (N_NODES / 4);
        for (int w = tid; w < N_NODES / 4; w += 1024) crow[w] = hist[w];
    } else if (b < BHIST + 8) {                       // W1 -> B-fragment pack
        int idx  = (b - BHIST) * 1024 + tid;          // [0, 8192)
        int lane = idx & 63;
        int slot = idx >> 6;
        int t    = slot >> 2;                         // n-tile
        int ks   = slot & 3;                          // k-step
        int quad = lane >> 4;
        int n    = t * 16 + (lane & 15);
        unsigned int us[8];
#pragma unroll
        for (int j = 0; j < 8; j++) {
            int k = ks * 32 + quad * 8 + j;
            float v = (n < D_HID) ? W1[(size_t)k * D_HID + n] : 0.f;
            us[j] = f2bf(v);
        }
        uint4 p;
        p.x = us[0] | (us[1] << 16);
        p.y = us[2] | (us[3] << 16);
        p.z = us[4] | (us[5] << 16);
        p.w = us[6] | (us[7] << 16);
        ((uint4*)b_pk)[idx] = p;
    } else {                                          // pad b1 / W2 to 512
        if (tid < 512) {
            b1p[tid] = (tid < D_HID) ? b1[tid] : 0.f;
            w2p[tid] = (tid < D_HID) ? W2[tid] : 0.f;
        }
    }
}

// Per-word (4-node) prefix over the 64 block-counts (in-place: coff becomes
// offsets), deg[n] = totals. Fully coalesced u32 accesses.
__global__ __launch_bounds__(256) void k_scan(unsigned int* __restrict__ coffw,
                                              int* __restrict__ deg) {
    const int t = blockIdx.x * 256 + threadIdx.x;     // word index (4 nodes)
    if (t >= N_NODES / 4) return;
    unsigned int run0 = 0, run1 = 0, run2 = 0, run3 = 0;
#pragma unroll 8
    for (int b = 0; b < BHIST; b++) {
        size_t idx = (size_t)b * (N_NODES / 4) + t;
        unsigned int c = coffw[idx];
        coffw[idx] = run0 | (run1 << 8) | (run2 << 16) | (run3 << 24);
        run0 += c & 0xffu;
        run1 += (c >> 8) & 0xffu;
        run2 += (c >> 16) & 0xffu;
        run3 += (c >> 24) & 0xffu;
    }
    int4 d;
    d.x = (int)run0; d.y = (int)run1; d.z = (int)run2; d.w = (int)run3;
    *(int4*)&deg[t * 4] = d;
}

// Padded-CSR scatter: block b (1:1 with hist block b) stages its 50KB coff
// row in LDS sequentially, then 4 edges/thread with LDS offset lookups --
// no random global gathers (R19 lesson). Blocks [BHIST,..): xd conversion.
__global__ __launch_bounds__(1024) void k_fill(const int* __restrict__ src,
                                               const int* __restrict__ dst,
                                               const unsigned char* __restrict__ coff,
                                               const unsigned char* __restrict__ lrank,
                                               const int* __restrict__ deg,
                                               const float* __restrict__ x,
                                               unsigned short* __restrict__ csrp,
                                               uint2* __restrict__ xd) {
    const int b = blockIdx.x, tid = threadIdx.x;
    if (b < BHIST) {                                  // scatter, LDS-staged row
        __shared__ unsigned char lcoff[N_NODES];      // 50 KB
        const unsigned int* crow =
            (const unsigned int*)coff + (size_t)b * (N_NODES / 4);
        for (int w = tid; w < N_NODES / 4; w += 1024)
            ((unsigned int*)lcoff)[w] = crow[w];
        __syncthreads();
        const int base = b * EPB;
        for (int i = tid * 4; i < EPB; i += 4096) {
            int4 s4 = *(const int4*)&src[base + i];
            int4 d4 = *(const int4*)&dst[base + i];
            uchar4 lr = *(const uchar4*)&lrank[base + i];
            int r0 = (int)lcoff[d4.x] + (int)lr.x;
            int r1 = (int)lcoff[d4.y] + (int)lr.y;
            int r2 = (int)lcoff[d4.z] + (int)lr.z;
            int r3 = (int)lcoff[d4.w] + (int)lr.w;
            if (r0 < CSTRIDE) csrp[d4.x * CSTRIDE + r0] = (unsigned short)s4.x;
            if (r1 < CSTRIDE) csrp[d4.y * CSTRIDE + r1] = (unsigned short)s4.y;
            if (r2 < CSTRIDE) csrp[d4.z * CSTRIDE + r2] = (unsigned short)s4.z;
            if (r3 < CSTRIDE) csrp[d4.w * CSTRIDE + r3] = (unsigned short)s4.w;
        }
    } else {                                          // xd = bf16(dinv*x)
        int gid = (b - BHIST) * 1024 + tid;
        for (int i = gid; i < N_NODES * D_FEAT / 4; i += CONVB * 1024) {
            float dv = rsqrtf((float)(deg[i >> 5] + 1));
            float4 v = ((const float4*)x)[i];
            uint2 o;
            o.x = f2bf(dv * v.x) | (f2bf(dv * v.y) << 16);
            o.y = f2bf(dv * v.z) | (f2bf(dv * v.w) << 16);
            xd[i] = o;
        }
    }
}

// Fused gather + bf16-MFMA MLP. Block = 16 nodes, 4 waves. Gather is
// QUARTER-WAVE-PER-NODE: 16 lanes own one node; lane p holds 16B of the row;
// 4-edge unroll -> 4 independent row loads in flight per quarter. Inner loop
// is pure index->row->add; indices are ushort (one 8B load per 4 edges).
__global__ __launch_bounds__(256, 8) void k_gcn1(const uint4* __restrict__ xd4,
                                                 const unsigned short* __restrict__ csrp,
                                                 const int* __restrict__ deg,
                                                 const unsigned short* __restrict__ b_pk,
                                                 const float* __restrict__ b1p,
                                                 const float* __restrict__ w2p,
                                                 float* __restrict__ zd) {
    __shared__ unsigned short A[16][136];   // bf16 rows; 272B stride, 2-way alias = free
    __shared__ float red[4][16];
    const int t = threadIdx.x;
    const int node0 = blockIdx.x * 16;      // 50000 = 16 * 3125
    const int wv = t >> 6, lane = t & 63;
    const int q = lane >> 4, p = lane & 15;

    // ---- Phase 1: gather; quarter q of wave wv owns node n = wv*4+q ----
    {
        const int n = wv * 4 + q;
        const int node = node0 + n;
        int dg = deg[node];
        uint4 su = xd4[(size_t)node * 16 + p];        // self-loop row, prefetched
        if (dg > CSTRIDE) dg = CSTRIDE;     // never fires; memory-safety guard
        const int base = node * CSTRIDE;
        float acc[8];
#pragma unroll
        for (int j = 0; j < 8; j++) acc[j] = 0.f;

        int e = 0;
        for (; e + 4 <= dg; e += 4) {       // 1 ushort4 index load + 4 rows in flight
            ushort4 s4 = *(const ushort4*)&csrp[base + e];
            uint4 u0 = xd4[(size_t)s4.x * 16 + p];
            uint4 u1 = xd4[(size_t)s4.y * 16 + p];
            uint4 u2 = xd4[(size_t)s4.z * 16 + p];
            uint4 u3 = xd4[(size_t)s4.w * 16 + p];
            add8(acc, u0);
            add8(acc, u1);
            add8(acc, u2);
            add8(acc, u3);
        }
        for (; e < dg; e++) {
            int s = csrp[base + e];
            uint4 u = xd4[(size_t)s * 16 + p];
            add8(acc, u);
        }

        // self-loop + finalize: A[n] = bf16( di * (acc + xd[node]) )
        const float di = rsqrtf((float)(dg + 1));
        uint4 o;
        o.x = f2bf(di * (acc[0] + bf_lo(su.x))) |
              (f2bf(di * (acc[1] + bf_hi(su.x))) << 16);
        o.y = f2bf(di * (acc[2] + bf_lo(su.y))) |
              (f2bf(di * (acc[3] + bf_hi(su.y))) << 16);
        o.z = f2bf(di * (acc[4] + bf_lo(su.z))) |
              (f2bf(di * (acc[5] + bf_hi(su.z))) << 16);
        o.w = f2bf(di * (acc[6] + bf_lo(su.w))) |
              (f2bf(di * (acc[7] + bf_hi(su.w))) << 16);
        *(uint4*)&A[n][p * 8] = o;
    }
    __syncthreads();

    // ---- Phase 2: D[16][512] via 16x16x32 bf16 MFMA; wave owns 8 n-tiles ----
    bf16x8 afr[4];
#pragma unroll
    for (int ks = 0; ks < 4; ks++)
        afr[ks] = *(const bf16x8*)&A[p][ks * 32 + q * 8];

    const bf16x8* __restrict__ bpk = (const bf16x8*)b_pk;
    f32x4 acc[8];
#pragma unroll
    for (int tt = 0; tt < 8; tt++) acc[tt] = (f32x4){0.f, 0.f, 0.f, 0.f};
#pragma unroll
    for (int tt = 0; tt < 8; tt++) {
        const int tile_n = wv * 8 + tt;
#pragma unroll
        for (int ks = 0; ks < 4; ks++) {
            bf16x8 bfr = bpk[(size_t)(tile_n * 4 + ks) * 64 + lane];
            acc[tt] = __builtin_amdgcn_mfma_f32_16x16x32_bf16(afr[ks], bfr, acc[tt], 0, 0, 0);
        }
    }

    // epilogue: zd-partial = relu(D + b1) . W2   (C/D: col=p, row=q*4+r)
    float zp[4] = {0.f, 0.f, 0.f, 0.f};
#pragma unroll
    for (int tt = 0; tt < 8; tt++) {
        const int c = (wv * 8 + tt) * 16 + p;
        const float b1v = b1p[c];
        const float w2v = w2p[c];
#pragma unroll
        for (int r = 0; r < 4; r++)
            zp[r] += fmaxf(acc[tt][r] + b1v, 0.f) * w2v;
    }
#pragma unroll
    for (int off = 1; off < 16; off <<= 1) {
#pragma unroll
        for (int r = 0; r < 4; r++) zp[r] += __shfl_xor(zp[r], off);
    }
    if (p == 0) {
#pragma unroll
        for (int r = 0; r < 4; r++) red[wv][q * 4 + r] = zp[r];
    }
    __syncthreads();
    if (t < 16) {
        int node = node0 + t;
        float zz = red[0][t] + red[1][t] + red[2][t] + red[3][t];
        zd[node] = rsqrtf((float)(deg[node] + 1)) * zz;
    }
}

// Layer-2 scalar gather: 16 lanes per node, shuffle-reduce (zd 200KB, L2-hot).
__global__ __launch_bounds__(256) void k_gz(const unsigned short* __restrict__ csrp,
                                            const int* __restrict__ deg,
                                            const float* __restrict__ zd,
                                            const float* __restrict__ b2,
                                            float* __restrict__ out) {
    const int node = blockIdx.x * 16 + (threadIdx.x >> 4);
    const int l = threadIdx.x & 15;
    int dg = deg[node];
    if (dg > CSTRIDE) dg = CSTRIDE;
    const int base = node * CSTRIDE;
    float s = 0.f;
    for (int e = l; e < dg; e += 16) s += zd[csrp[base + e]];
#pragma unroll
    for (int off = 1; off < 16; off <<= 1) s += __shfl_xor(s, off);
    if (l == 0) {
        float di = rsqrtf((float)(dg + 1));
        out[node] = di * (s + zd[node]) + b2[0];
    }
}

extern "C" void kernel_launch(void* const* d_in, const int* in_sizes, int n_in,
                              void* d_out, int out_size, void* d_ws, size_t ws_size,
                              hipStream_t stream) {
    const float* x  = (const float*)d_in[0];
    const int*   ei = (const int*)d_in[1];     // [2, E]: row 0 = src, row 1 = dst
    const float* W1 = (const float*)d_in[2];
    const float* b1 = (const float*)d_in[3];
    const float* W2 = (const float*)d_in[4];
    const float* b2 = (const float*)d_in[5];
    float* out = (float*)d_out;

    const int* src = ei;
    const int* dst = ei + N_EDGES;

    // Workspace layout (~24.5 MB).
    uint2* xd            = (uint2*)d_ws;                       // 1,600,000 uint2 (12.8 MB)
    unsigned short* b_pk = (unsigned short*)(xd + 1600000);    // 65,536 bf16 (128 KB)
    float* b1p    = (float*)(b_pk + 65536);                    // 512
    float* w2p    = b1p + 512;                                 // 512
    float* zd     = w2p + 512;                                 // 50000
    int* deg      = (int*)(zd + N_NODES);                      // 50000
    unsigned char* coff  = (unsigned char*)(deg + N_NODES);    // 64*50000 u8 (3.2 MB)
    unsigned char* lrank = coff + (size_t)BHIST * N_NODES;     // 800,000 u8
    unsigned short* csrp = (unsigned short*)(lrank + N_EDGES); // 3,200,000 u16 (6.4 MB)

    k_hist<<<BHIST + 9, 1024, 0, stream>>>(dst, W1, b1, W2, coff, lrank,
                                           b_pk, b1p, w2p);
    k_scan<<<(N_NODES / 4 + 255) / 256, 256, 0, stream>>>((unsigned int*)coff, deg);
    k_fill<<<BHIST + CONVB, 1024, 0, stream>>>(src, dst, coff, lrank, deg, x,
                                               csrp, xd);
    k_gcn1<<<NTILES, 256, 0, stream>>>((const uint4*)xd, csrp, deg,
                                       b_pk, b1p, w2p, zd);
    k_gz  <<<NTILES, 256, 0, stream>>>(csrp, deg, zd, b2, out);
}

// Round 5
// 153.123 us; speedup vs baseline: 1.1948x; 1.0060x over previous
//
#include <hip/hip_runtime.h>

// 2-layer GCN, group-padded-exact-CSR gather + bf16-MFMA, 5 dispatches.
//
// LESSON (R6-R8, measured): grid.sync() costs ~250-300us EACH on MI355X.
// LESSON (R9): mean degree 16 -- hide gather latency via INDEPENDENT chains
// (quarter-wave-per-node), not unroll depth.
// LESSON (R13/R14): scatter fused into the atomic pass regresses.
// LESSON (R15-R17, measured): k_gcn1 pinned ~46.5us by the random-gather
// path -- insensitive to occupancy, per-edge VALU work, index width.
// 84MB HBM-side of 205MB logical, structural for a 12.8MB working set vs
// 4MB/XCD L2 on a random graph.
// LESSON (R19, measured): random small accesses into tables that exceed the
// per-XCD L2 thrash and cost 10+MB of HBM re-fetch. Keep hot tables <4MB.
// LESSON (R20, measured): LDS-histogram rank beats 800K device atomics.
// LESSON (R21, measured): build kernels at 1 wave/SIMD are latency-bound;
// 1024thr + int4 loads = -12.2us.
// LESSON (R22, measured): u8 rank/coff + LDS-staged coff rows = -6.9us
// (160.9 -> 154.0). Build-path traffic matters.
// R23: the last big suspect is the csrp scatter -- 800K random 2B stores
// into a 6.4MB table (> 4MB/XCD L2): write-allocate line fills + capacity
// thrash + kernel-end drain. Replace padded CSR (64 slots/node, 6.4MB) with
// GROUP-PADDED EXACT CSR: 49 groups x 1024 nodes, fixed 24576-slot region
// per group (sum(deg)~16384+align, ~64 sigma margin, per-store bound check
// for safety), per-node starts 4-slot aligned so ushort4 index loads keep
// working. Table = 2.4MB -> L2-RESIDENT scatter. Group structure makes the
// node scan BLOCK-LOCAL in k_scan (absolute rstart4, no extra dispatch).
// Scatter TLP x5 (320 blocks). k_gcn1/k_gz read rstart4[node] instead of
// node*64.
//
//   k_hist : 64 LDS-histogram blocks @1024thr (u8 lrank, u8 counts)
//            | 8 W1-pack blocks | 1 pad block
//   k_scan : per word: prefix over 64 blocks (in-place coff) + deg;
//            per group (= block): local scan -> absolute rstart4[n]
//   k_fill : blocks [0,320): stage coff row in LDS; csre[rstart4[dst]+
//            lcoff[dst]+lrank[e]] = (u16)src, 2500 edges/block
//            blocks [320,712): xd = bf16(rsqrt(deg+1)*x) grid-stride
//   k_gcn1 : per 16-node tile: gather A[n]=dinv_n*(sum xd[s] + xd[n]) -> LDS,
//            zd = dinv * ( relu(A@W1 + b1) @ W2 ) via mfma_f32_16x16x32_bf16
//   k_gz   : out[i] = dinv[i]*(sum_{s in N(i)} zd[s] + zd[i]) + b2

#define N_NODES 50000
#define N_EDGES 800000
#define D_FEAT  128
#define D_HID   500
#define NTILES  3125         // 50000 / 16
#define BHIST   64           // histogram blocks
#define EPB     12500        // edges per histogram block
#define SPLIT   5            // scatter blocks per histogram block
#define SB      (BHIST * SPLIT)   // 320 scatter blocks
#define EPSB    (EPB / SPLIT)     // 2500 edges per scatter block (mult of 4)
#define CONVB   392          // conversion blocks in k_fill (1024 thr each)
#define NGROUP  49           // node groups of 1024 (last = 848)
#define GSTRIDE 24576        // csre slots per group (sum deg ~16384, huge margin)
#define CSRE_SLOTS (NGROUP * GSTRIDE)   // 1,204,224 slots (2.41 MB)

typedef __bf16 bf16x8 __attribute__((ext_vector_type(8)));
typedef float  f32x4  __attribute__((ext_vector_type(4)));

static __device__ inline unsigned int f2bf(float f) {   // fp32 -> bf16 bits, RTNE
    unsigned int u = __float_as_uint(f);
    return (u + 0x7fffu + ((u >> 16) & 1u)) >> 16;
}
static __device__ inline float bf_lo(unsigned int u) { return __uint_as_float(u << 16); }
static __device__ inline float bf_hi(unsigned int u) { return __uint_as_float(u & 0xffff0000u); }

static __device__ inline void add8(float* acc, uint4 u) {
    acc[0] += bf_lo(u.x);
    acc[1] += bf_hi(u.x);
    acc[2] += bf_lo(u.y);
    acc[3] += bf_hi(u.y);
    acc[4] += bf_lo(u.z);
    acc[5] += bf_hi(u.z);
    acc[6] += bf_lo(u.w);
    acc[7] += bf_hi(u.w);
}

// ---- k_hist: [0,BHIST) LDS-histogram rank @1024thr | 8 W1-pack | 1 pad ----
// Histogram packs 4 nodes per u32 word (u8 counts, Poisson lambda=0.25/block).
__global__ __launch_bounds__(1024) void k_hist(const int* __restrict__ dst,
                                               const float* __restrict__ W1,
                                               const float* __restrict__ b1,
                                               const float* __restrict__ W2,
                                               unsigned char* __restrict__ coff,
                                               unsigned char* __restrict__ lrank,
                                               unsigned short* __restrict__ b_pk,
                                               float* __restrict__ b1p,
                                               float* __restrict__ w2p) {
    __shared__ unsigned int hist[N_NODES / 4];        // 12500 words = 50 KB
    const int b = blockIdx.x, tid = threadIdx.x;
    if (b < BHIST) {                                  // histogram + local rank
        for (int w = tid; w < N_NODES / 4; w += 1024) hist[w] = 0u;
        __syncthreads();
        const int base = b * EPB;
        for (int i = tid * 4; i < EPB; i += 4096) {   // 4 indep atomic chains
            int4 d4 = *(const int4*)&dst[base + i];
            unsigned int s0 = (unsigned int)(d4.x & 3) * 8u;
            unsigned int s1 = (unsigned int)(d4.y & 3) * 8u;
            unsigned int s2 = (unsigned int)(d4.z & 3) * 8u;
            unsigned int s3 = (unsigned int)(d4.w & 3) * 8u;
            unsigned int r0 = atomicAdd(&hist[d4.x >> 2], 1u << s0);
            unsigned int r1 = atomicAdd(&hist[d4.y >> 2], 1u << s1);
            unsigned int r2 = atomicAdd(&hist[d4.z >> 2], 1u << s2);
            unsigned int r3 = atomicAdd(&hist[d4.w >> 2], 1u << s3);
            uchar4 lr;
            lr.x = (unsigned char)((r0 >> s0) & 0xffu);
            lr.y = (unsigned char)((r1 >> s1) & 0xffu);
            lr.z = (unsigned char)((r2 >> s2) & 0xffu);
            lr.w = (unsigned char)((r3 >> s3) & 0xffu);
            *(uchar4*)&lrank[base + i] = lr;
        }
        __syncthreads();
        unsigned int* crow = (unsigned int*)coff + (size_t)b * (N_NODES / 4);
        for (int w = tid; w < N_NODES / 4; w += 1024) crow[w] = hist[w];
    } else if (b < BHIST + 8) {                       // W1 -> B-fragment pack
        int idx  = (b - BHIST) * 1024 + tid;          // [0, 8192)
        int lane = idx & 63;
        int slot = idx >> 6;
        int t    = slot >> 2;                         // n-tile
        int ks   = slot & 3;                          // k-step
        int quad = lane >> 4;
        int n    = t * 16 + (lane & 15);
        unsigned int us[8];
#pragma unroll
        for (int j = 0; j < 8; j++) {
            int k = ks * 32 + quad * 8 + j;
            float v = (n < D_HID) ? W1[(size_t)k * D_HID + n] : 0.f;
            us[j] = f2bf(v);
        }
        uint4 p;
        p.x = us[0] | (us[1] << 16);
        p.y = us[2] | (us[3] << 16);
        p.z = us[4] | (us[5] << 16);
        p.w = us[6] | (us[7] << 16);
        ((uint4*)b_pk)[idx] = p;
    } else {                                          // pad b1 / W2 to 512
        if (tid < 512) {
            b1p[tid] = (tid < D_HID) ? b1[tid] : 0.f;
            w2p[tid] = (tid < D_HID) ? W2[tid] : 0.f;
        }
    }
}

// Per-word (4-node) prefix over the 64 block-counts (in-place coff -> block
// offsets), deg[n] = totals, AND block-local (= group-local) scan of
// 4-aligned slot counts -> ABSOLUTE rstart4[n] = g*GSTRIDE + local prefix.
// Block g covers nodes [g*1024, g*1024+1024); scan never crosses blocks.
__global__ __launch_bounds__(256) void k_scan(unsigned int* __restrict__ coffw,
                                              int* __restrict__ deg,
                                              unsigned int* __restrict__ rstart4) {
    __shared__ unsigned int ps[256];
    const int g = blockIdx.x, tid = threadIdx.x;
    const int idx = g * 256 + tid;                    // word index (4 nodes)
    const bool live = idx < N_NODES / 4;
    unsigned int run0 = 0, run1 = 0, run2 = 0, run3 = 0;
    if (live) {
#pragma unroll 8
        for (int b = 0; b < BHIST; b++) {
            size_t i = (size_t)b * (N_NODES / 4) + idx;
            unsigned int c = coffw[i];
            coffw[i] = run0 | (run1 << 8) | (run2 << 16) | (run3 << 24);
            run0 += c & 0xffu;
            run1 += (c >> 8) & 0xffu;
            run2 += (c >> 16) & 0xffu;
            run3 += (c >> 24) & 0xffu;
        }
        int4 d;
        d.x = (int)run0; d.y = (int)run1; d.z = (int)run2; d.w = (int)run3;
        *(int4*)&deg[idx * 4] = d;
    }
    // 4-aligned slot counts + in-thread exclusive prefix
    unsigned int s0 = (run0 + 3u) & ~3u, s1 = (run1 + 3u) & ~3u;
    unsigned int s2 = (run2 + 3u) & ~3u, s3 = (run3 + 3u) & ~3u;
    unsigned int tot = live ? (s0 + s1 + s2 + s3) : 0u;
    ps[tid] = tot;
    __syncthreads();
    for (int off = 1; off < 256; off <<= 1) {         // inclusive block scan
        unsigned int v = (tid >= off) ? ps[tid - off] : 0u;
        __syncthreads();
        ps[tid] += v;
        __syncthreads();
    }
    if (live) {
        unsigned int base = (unsigned int)g * GSTRIDE + (ps[tid] - tot);
        uint4 r;
        r.x = base;
        r.y = base + s0;
        r.z = base + s0 + s1;
        r.w = base + s0 + s1 + s2;
        *(uint4*)&rstart4[idx * 4] = r;
    }
}

// Scatter into the 2.4MB L2-RESIDENT exact CSR: block b serves hist row
// b/SPLIT (coff row staged in LDS), 2500 edges, 4/thread, 1 iteration.
// Blocks [SB, SB+CONVB): xd = bf16(dinv*x) conversion.
__global__ __launch_bounds__(1024) void k_fill(const int* __restrict__ src,
                                               const int* __restrict__ dst,
                                               const unsigned char* __restrict__ coff,
                                               const unsigned char* __restrict__ lrank,
                                               const unsigned int* __restrict__ rstart4,
                                               const int* __restrict__ deg,
                                               const float* __restrict__ x,
                                               unsigned short* __restrict__ csre,
                                               uint2* __restrict__ xd) {
    const int b = blockIdx.x, tid = threadIdx.x;
    if (b < SB) {                                     // scatter, LDS-staged row
        __shared__ unsigned char lcoff[N_NODES];      // 50 KB
        const int hb = b / SPLIT;
        const unsigned int* crow =
            (const unsigned int*)coff + (size_t)hb * (N_NODES / 4);
        for (int w = tid; w < N_NODES / 4; w += 1024)
            ((unsigned int*)lcoff)[w] = crow[w];
        __syncthreads();
        const int base = b * EPSB;                    // mult of 4 (2500)
        for (int i = tid * 4; i < EPSB; i += 4096) {  // exactly 1 iter, tid<625
            int4 s4 = *(const int4*)&src[base + i];
            int4 d4 = *(const int4*)&dst[base + i];
            uchar4 lr = *(const uchar4*)&lrank[base + i];
            unsigned int t0 = rstart4[d4.x] + (unsigned int)lcoff[d4.x] + lr.x;
            unsigned int t1 = rstart4[d4.y] + (unsigned int)lcoff[d4.y] + lr.y;
            unsigned int t2 = rstart4[d4.z] + (unsigned int)lcoff[d4.z] + lr.z;
            unsigned int t3 = rstart4[d4.w] + (unsigned int)lcoff[d4.w] + lr.w;
            if (t0 < CSRE_SLOTS) csre[t0] = (unsigned short)s4.x;
            if (t1 < CSRE_SLOTS) csre[t1] = (unsigned short)s4.y;
            if (t2 < CSRE_SLOTS) csre[t2] = (unsigned short)s4.z;
            if (t3 < CSRE_SLOTS) csre[t3] = (unsigned short)s4.w;
        }
    } else {                                          // xd = bf16(dinv*x)
        int gid = (b - SB) * 1024 + tid;
        for (int i = gid; i < N_NODES * D_FEAT / 4; i += CONVB * 1024) {
            float dv = rsqrtf((float)(deg[i >> 5] + 1));
            float4 v = ((const float4*)x)[i];
            uint2 o;
            o.x = f2bf(dv * v.x) | (f2bf(dv * v.y) << 16);
            o.y = f2bf(dv * v.z) | (f2bf(dv * v.w) << 16);
            xd[i] = o;
        }
    }
}

// Fused gather + bf16-MFMA MLP. Block = 16 nodes, 4 waves. Gather is
// QUARTER-WAVE-PER-NODE: 16 lanes own one node; lane p holds 16B of the row;
// 4-edge unroll -> 4 independent row loads in flight per quarter. Per-node
// base comes from rstart4 (4-slot aligned -> ushort4 loads stay 8B-aligned).
__global__ __launch_bounds__(256, 8) void k_gcn1(const uint4* __restrict__ xd4,
                                                 const unsigned short* __restrict__ csre,
                                                 const unsigned int* __restrict__ rstart4,
                                                 const int* __restrict__ deg,
                                                 const unsigned short* __restrict__ b_pk,
                                                 const float* __restrict__ b1p,
                                                 const float* __restrict__ w2p,
                                                 float* __restrict__ zd) {
    __shared__ unsigned short A[16][136];   // bf16 rows; 272B stride, 2-way alias = free
    __shared__ float red[4][16];
    const int t = threadIdx.x;
    const int node0 = blockIdx.x * 16;      // 50000 = 16 * 3125
    const int wv = t >> 6, lane = t & 63;
    const int q = lane >> 4, p = lane & 15;

    // ---- Phase 1: gather; quarter q of wave wv owns node n = wv*4+q ----
    {
        const int n = wv * 4 + q;
        const int node = node0 + n;
        int dg = deg[node];
        const unsigned int base = rstart4[node];
        uint4 su = xd4[(size_t)node * 16 + p];        // self-loop row, prefetched
        if (dg > 64) dg = 64;               // never fires; memory-safety guard
        float acc[8];
#pragma unroll
        for (int j = 0; j < 8; j++) acc[j] = 0.f;

        int e = 0;
        for (; e + 4 <= dg; e += 4) {       // 1 ushort4 index load + 4 rows in flight
            ushort4 s4 = *(const ushort4*)&csre[base + e];
            uint4 u0 = xd4[(size_t)s4.x * 16 + p];
            uint4 u1 = xd4[(size_t)s4.y * 16 + p];
            uint4 u2 = xd4[(size_t)s4.z * 16 + p];
            uint4 u3 = xd4[(size_t)s4.w * 16 + p];
            add8(acc, u0);
            add8(acc, u1);
            add8(acc, u2);
            add8(acc, u3);
        }
        for (; e < dg; e++) {
            int s = csre[base + e];
            uint4 u = xd4[(size_t)s * 16 + p];
            add8(acc, u);
        }

        // self-loop + finalize: A[n] = bf16( di * (acc + xd[node]) )
        const float di = rsqrtf((float)(dg + 1));
        uint4 o;
        o.x = f2bf(di * (acc[0] + bf_lo(su.x))) |
              (f2bf(di * (acc[1] + bf_hi(su.x))) << 16);
        o.y = f2bf(di * (acc[2] + bf_lo(su.y))) |
              (f2bf(di * (acc[3] + bf_hi(su.y))) << 16);
        o.z = f2bf(di * (acc[4] + bf_lo(su.z))) |
              (f2bf(di * (acc[5] + bf_hi(su.z))) << 16);
        o.w = f2bf(di * (acc[6] + bf_lo(su.w))) |
              (f2bf(di * (acc[7] + bf_hi(su.w))) << 16);
        *(uint4*)&A[n][p * 8] = o;
    }
    __syncthreads();

    // ---- Phase 2: D[16][512] via 16x16x32 bf16 MFMA; wave owns 8 n-tiles ----
    bf16x8 afr[4];
#pragma unroll
    for (int ks = 0; ks < 4; ks++)
        afr[ks] = *(const bf16x8*)&A[p][ks * 32 + q * 8];

    const bf16x8* __restrict__ bpk = (const bf16x8*)b_pk;
    f32x4 acc[8];
#pragma unroll
    for (int tt = 0; tt < 8; tt++) acc[tt] = (f32x4){0.f, 0.f, 0.f, 0.f};
#pragma unroll
    for (int tt = 0; tt < 8; tt++) {
        const int tile_n = wv * 8 + tt;
#pragma unroll
        for (int ks = 0; ks < 4; ks++) {
            bf16x8 bfr = bpk[(size_t)(tile_n * 4 + ks) * 64 + lane];
            acc[tt] = __builtin_amdgcn_mfma_f32_16x16x32_bf16(afr[ks], bfr, acc[tt], 0, 0, 0);
        }
    }

    // epilogue: zd-partial = relu(D + b1) . W2   (C/D: col=p, row=q*4+r)
    float zp[4] = {0.f, 0.f, 0.f, 0.f};
#pragma unroll
    for (int tt = 0; tt < 8; tt++) {
        const int c = (wv * 8 + tt) * 16 + p;
        const float b1v = b1p[c];
        const float w2v = w2p[c];
#pragma unroll
        for (int r = 0; r < 4; r++)
            zp[r] += fmaxf(acc[tt][r] + b1v, 0.f) * w2v;
    }
#pragma unroll
    for (int off = 1; off < 16; off <<= 1) {
#pragma unroll
        for (int r = 0; r < 4; r++) zp[r] += __shfl_xor(zp[r], off);
    }
    if (p == 0) {
#pragma unroll
        for (int r = 0; r < 4; r++) red[wv][q * 4 + r] = zp[r];
    }
    __syncthreads();
    if (t < 16) {
        int node = node0 + t;
        float zz = red[0][t] + red[1][t] + red[2][t] + red[3][t];
        zd[node] = rsqrtf((float)(deg[node] + 1)) * zz;
    }
}

// Layer-2 scalar gather: 16 lanes per node, shuffle-reduce (zd 200KB, L2-hot).
__global__ __launch_bounds__(256) void k_gz(const unsigned short* __restrict__ csre,
                                            const unsigned int* __restrict__ rstart4,
                                            const int* __restrict__ deg,
                                            const float* __restrict__ zd,
                                            const float* __restrict__ b2,
                                            float* __restrict__ out) {
    const int node = blockIdx.x * 16 + (threadIdx.x >> 4);
    const int l = threadIdx.x & 15;
    int dg = deg[node];
    if (dg > 64) dg = 64;
    const unsigned int base = rstart4[node];
    float s = 0.f;
    for (int e = l; e < dg; e += 16) s += zd[csre[base + e]];
#pragma unroll
    for (int off = 1; off < 16; off <<= 1) s += __shfl_xor(s, off);
    if (l == 0) {
        float di = rsqrtf((float)(dg + 1));
        out[node] = di * (s + zd[node]) + b2[0];
    }
}

extern "C" void kernel_launch(void* const* d_in, const int* in_sizes, int n_in,
                              void* d_out, int out_size, void* d_ws, size_t ws_size,
                              hipStream_t stream) {
    const float* x  = (const float*)d_in[0];
    const int*   ei = (const int*)d_in[1];     // [2, E]: row 0 = src, row 1 = dst
    const float* W1 = (const float*)d_in[2];
    const float* b1 = (const float*)d_in[3];
    const float* W2 = (const float*)d_in[4];
    const float* b2 = (const float*)d_in[5];
    float* out = (float*)d_out;

    const int* src = ei;
    const int* dst = ei + N_EDGES;

    // Workspace layout (~20.5 MB).
    uint2* xd            = (uint2*)d_ws;                       // 1,600,000 uint2 (12.8 MB)
    unsigned short* b_pk = (unsigned short*)(xd + 1600000);    // 65,536 bf16 (128 KB)
    float* b1p    = (float*)(b_pk + 65536);                    // 512
    float* w2p    = b1p + 512;                                 // 512
    float* zd     = w2p + 512;                                 // 50000 (200 KB)
    int* deg      = (int*)(zd + N_NODES);                      // 50000 (200 KB)
    unsigned int* rstart4 = (unsigned int*)(deg + N_NODES);    // 50000 u32 (200 KB)
    unsigned char* coff  = (unsigned char*)(rstart4 + N_NODES);// 64*50000 u8 (3.2 MB)
    unsigned char* lrank = coff + (size_t)BHIST * N_NODES;     // 800,000 u8
    unsigned short* csre = (unsigned short*)(lrank + N_EDGES); // 1,204,224 u16 (2.41 MB)

    k_hist<<<BHIST + 9, 1024, 0, stream>>>(dst, W1, b1, W2, coff, lrank,
                                           b_pk, b1p, w2p);
    k_scan<<<NGROUP, 256, 0, stream>>>((unsigned int*)coff, deg, rstart4);
    k_fill<<<SB + CONVB, 1024, 0, stream>>>(src, dst, coff, lrank, rstart4,
                                            deg, x, csre, xd);
    k_gcn1<<<NTILES, 256, 0, stream>>>((const uint4*)xd, csre, rstart4, deg,
                                       b_pk, b1p, w2p, zd);
    k_gz  <<<NTILES, 256, 0, stream>>>(csre, rstart4, deg, zd, b2, out);
}